// Round 3
// baseline (3100.328 us; speedup 1.0000x reference)
//
#include <hip/hip_runtime.h>

#define N_NODES 100000
#define N_EDGES 3200000
#define D 128

#define K1      98        // coarse buckets: bucket = dst >> 10 (1024 nodes each)
#define NB      128       // nodes per reduce block (8 sub-blocks per coarse bucket)
#define CHUNK   2048      // edges per partition block
#define NCHUNK  1563      // ceil(N_EDGES / CHUNK)

// ---------------------------------------------------------------------------
// Workspace layout (bytes). Need ~51.3 MB; round-2 path proved ws >= 78 MB.
// ---------------------------------------------------------------------------
static const size_t OFF_SB    = 0;           // S bf16: N*D*2      = 25,600,000
static const size_t OFF_REC   = 25600000;    // E int2             = 25,600,000
static const size_t OFF_GHIST = 51200000;    // K1 ints
static const size_t OFF_BOFFS = 51201024;    // K1+1 ints
static const size_t OFF_GCUR  = 51202048;    // K1 ints

__device__ __forceinline__ unsigned short f2bf(float f) {
    unsigned u = __float_as_uint(f);
    return (unsigned short)((u + 0x7FFFu + ((u >> 16) & 1u)) >> 16);   // RNE
}

// ---------------------------------------------------------------------------
// S = X @ W, output bf16, features (2l, 2l+1) per lane (pairs for the
// 4 B/lane gathers in bucket_reduce). W staged in LDS; float2 ds_read per k.
// ---------------------------------------------------------------------------
__global__ __launch_bounds__(256) void gemm_xw(const float* __restrict__ X,
                                               const float* __restrict__ W,
                                               unsigned* __restrict__ Sb) { // uint = 2 bf16
    __shared__ float w_lds[D * D];      // 64 KB
    __shared__ float x_lds[4][D];

    for (int i = threadIdx.x; i < (D * D) / 4; i += 256)
        ((float4*)w_lds)[i] = ((const float4*)W)[i];
    __syncthreads();

    const int wave = threadIdx.x >> 6;
    const int lane = threadIdx.x & 63;

    for (int node = blockIdx.x * 4 + wave; node < N_NODES;
         node += gridDim.x * 4) {
        float2 xv = ((const float2*)(X + (size_t)node * D))[lane];
        x_lds[wave][2 * lane]     = xv.x;
        x_lds[wave][2 * lane + 1] = xv.y;

        float acc0 = 0.f, acc1 = 0.f;
#pragma unroll 8
        for (int k = 0; k < D; ++k) {
            float xk = x_lds[wave][k];                       // broadcast
            float2 w2 = ((const float2*)w_lds)[k * 64 + lane]; // b64, conflict-free
            acc0 += xk * w2.x;
            acc1 += xk * w2.y;
        }
        unsigned packed = (unsigned)f2bf(acc0) | ((unsigned)f2bf(acc1) << 16);
        Sb[(size_t)node * 64 + lane] = packed;               // 256 B/row, coalesced
    }
}

// ---------------------------------------------------------------------------
// Coarse histogram over K1 buckets (LDS hist, then one flush per block)
// ---------------------------------------------------------------------------
__global__ __launch_bounds__(256) void hist_coarse(const int* __restrict__ edst,
                                                   int* __restrict__ ghist) {
    __shared__ int h[K1];
    if (threadIdx.x < K1) h[threadIdx.x] = 0;
    __syncthreads();
    for (int e = blockIdx.x * 256 + threadIdx.x; e < N_EDGES; e += gridDim.x * 256)
        atomicAdd(&h[edst[e] >> 10], 1);
    __syncthreads();
    if (threadIdx.x < K1 && h[threadIdx.x]) atomicAdd(&ghist[threadIdx.x], h[threadIdx.x]);
}

// Exclusive scan of K1 counters -> boffs[0..K1], and gcursor = boffs copy.
__global__ __launch_bounds__(128) void scan_coarse(const int* __restrict__ ghist,
                                                   int* __restrict__ boffs,
                                                   int* __restrict__ gcursor) {
    __shared__ int sc[128];
    const int t = threadIdx.x;
    sc[t] = (t < K1) ? ghist[t] : 0;
    __syncthreads();
    for (int off = 1; off < 128; off <<= 1) {
        int v = (t >= off) ? sc[t - off] : 0;
        __syncthreads();
        sc[t] += v;
        __syncthreads();
    }
    if (t < K1) {
        int ex = (t == 0) ? 0 : sc[t - 1];
        boffs[t] = ex;
        gcursor[t] = ex;
    }
    if (t == K1) boffs[K1] = sc[K1 - 1];
}

// ---------------------------------------------------------------------------
// LDS-staged partition: one block per 2048-edge chunk. Bin records by coarse
// bucket in LDS, reserve global space with ONE atomic per (bucket,chunk),
// flush each bucket segment contiguously (coalesced full-ish lines).
// rec.x = src | (dst_local << 17), rec.y = val bits.
// ---------------------------------------------------------------------------
__global__ __launch_bounds__(256) void partition_edges(
        const int* __restrict__ esrc,
        const int* __restrict__ edst,
        const float* __restrict__ eval,
        int* __restrict__ gcursor,
        int2* __restrict__ rec_out) {
    __shared__ int  hist[K1];
    __shared__ int  lofs[K1];
    __shared__ int  gbase[K1];
    __shared__ int  sc[128];
    __shared__ int2 staged[CHUNK];            // 16 KB
    __shared__ unsigned char bkt[CHUNK];      // 2 KB

    const int t  = threadIdx.x;
    const int e0 = blockIdx.x * CHUNK;
    const int cnt = min(CHUNK, N_EDGES - e0);

    if (t < K1) hist[t] = 0;
    __syncthreads();

    int b[8], r[8], sv[8]; float vv[8];
#pragma unroll
    for (int j = 0; j < 8; ++j) {
        int idx = t + j * 256;
        if (idx < cnt) {
            int e = e0 + idx;
            int d = edst[e];
            sv[j] = esrc[e];
            vv[j] = eval[e];
            b[j]  = d >> 10;
            int dl = d & 1023;
            sv[j] |= (dl << 17);
            r[j] = atomicAdd(&hist[b[j]], 1);
        } else b[j] = -1;
    }
    __syncthreads();

    // exclusive scan of hist -> lofs; reserve global space per bucket
    sc[ (t < 128) ? t : 0 ];   // no-op to keep indices obvious
    if (t < 128) sc[t] = (t < K1) ? hist[t] : 0;
    __syncthreads();
    for (int off = 1; off < 128; off <<= 1) {
        int v = (t < 128 && t >= off) ? sc[t - off] : 0;
        __syncthreads();
        if (t < 128 && t >= off) sc[t] += v;
        __syncthreads();
    }
    if (t < K1) {
        lofs[t] = (t == 0) ? 0 : sc[t - 1];
        gbase[t] = hist[t] ? atomicAdd(&gcursor[t], hist[t]) : 0;
    }
    __syncthreads();

#pragma unroll
    for (int j = 0; j < 8; ++j) {
        if (b[j] >= 0) {
            int pos = lofs[b[j]] + r[j];
            staged[pos] = make_int2(sv[j], __float_as_int(vv[j]));
            bkt[pos] = (unsigned char)b[j];
        }
    }
    __syncthreads();

    for (int i = t; i < cnt; i += 256) {
        int bb = bkt[i];
        rec_out[gbase[bb] + (i - lofs[bb])] = staged[i];
    }
}

// ---------------------------------------------------------------------------
// Fused bin + reduce: block = (coarse bucket c, sub-range s of 128 nodes).
// LDS fp32 accumulator [128][128] = 64 KB. Stream the coarse bucket's
// records; lanes ballot membership; matching records: gather 4 B/lane from
// bf16 S row, ds_add_f32 into the node's LDS row. Epilogue adds bias.
// ---------------------------------------------------------------------------
__global__ __launch_bounds__(256) void bucket_reduce(
        const unsigned short* __restrict__ Sb,
        const int2* __restrict__ rec,
        const int* __restrict__ boffs,
        const float* __restrict__ bias,
        float* __restrict__ out) {
    __shared__ float acc[NB * D];             // 64 KB

    const int c = blockIdx.x >> 3;
    const int s = blockIdx.x & 7;
    const int nodeBase = c * 1024 + s * NB;
    const int lane = threadIdx.x & 63;
    const int wave = threadIdx.x >> 6;

    for (int i = threadIdx.x; i < (NB * D) / 4; i += 256)
        ((float4*)acc)[i] = make_float4(0.f, 0.f, 0.f, 0.f);
    __syncthreads();

    const int beg = boffs[c];
    const int end = boffs[c + 1];

    for (int base = beg + wave * 64; base < end; base += 4 * 64) {
        const int idx = base + lane;
        int rx = 0, ry = 0;
        bool valid = idx < end;
        if (valid) { int2 q = rec[idx]; rx = q.x; ry = q.y; }
        const int dl = (rx >> 17) & 1023;
        unsigned long long m = __ballot(valid && ((dl >> 7) == s));

        while (m) {
            int j0 = __ffsll((long long)m) - 1; m &= m - 1;
            int j1 = -1;
            if (m) { j1 = __ffsll((long long)m) - 1; m &= m - 1; }

            int   rx0 = __shfl(rx, j0);
            float v0  = __int_as_float(__shfl(ry, j0));
            int   row0 = (rx0 >> 17) & 127;
            unsigned p0 = *(const unsigned*)(Sb + ((size_t)(rx0 & 0x1FFFF) << 7) + 2 * lane);

            unsigned p1 = 0; int row1 = 0; float v1 = 0.f;
            if (j1 >= 0) {
                int rx1 = __shfl(rx, j1);
                v1  = __int_as_float(__shfl(ry, j1));
                row1 = (rx1 >> 17) & 127;
                p1 = *(const unsigned*)(Sb + ((size_t)(rx1 & 0x1FFFF) << 7) + 2 * lane);
            }

            float f0a = __uint_as_float(p0 << 16);
            float f0b = __uint_as_float(p0 & 0xFFFF0000u);
            atomicAdd(&acc[row0 * D + 2 * lane],     v0 * f0a);
            atomicAdd(&acc[row0 * D + 2 * lane + 1], v0 * f0b);
            if (j1 >= 0) {
                float f1a = __uint_as_float(p1 << 16);
                float f1b = __uint_as_float(p1 & 0xFFFF0000u);
                atomicAdd(&acc[row1 * D + 2 * lane],     v1 * f1a);
                atomicAdd(&acc[row1 * D + 2 * lane + 1], v1 * f1b);
            }
        }
    }
    __syncthreads();

    float2 b2 = ((const float2*)bias)[lane];
    for (int row = wave; row < NB; row += 4) {
        int node = nodeBase + row;
        if (node < N_NODES) {
            float2 r2 = make_float2(acc[row * D + 2 * lane]     + b2.x,
                                    acc[row * D + 2 * lane + 1] + b2.y);
            ((float2*)(out + (size_t)node * D))[lane] = r2;
        }
    }
}

extern "C" void kernel_launch(void* const* d_in, const int* in_sizes, int n_in,
                              void* d_out, int out_size, void* d_ws, size_t ws_size,
                              hipStream_t stream) {
    const float* X    = (const float*)d_in[0];
    const int*   esrc = (const int*)  d_in[1];
    const int*   edst = (const int*)  d_in[2];
    const float* eval = (const float*)d_in[3];
    const float* W    = (const float*)d_in[4];
    const float* bias = (const float*)d_in[5];
    float* out = (float*)d_out;

    char* ws = (char*)d_ws;
    unsigned*       SbW    = (unsigned*)      (ws + OFF_SB);
    unsigned short* Sb     = (unsigned short*)(ws + OFF_SB);
    int2*           recs   = (int2*)          (ws + OFF_REC);
    int*            ghist  = (int*)           (ws + OFF_GHIST);
    int*            boffs  = (int*)           (ws + OFF_BOFFS);
    int*            gcur   = (int*)           (ws + OFF_GCUR);

    // S = X @ W  (bf16 output)
    gemm_xw<<<2048, 256, 0, stream>>>(X, W, SbW);

    // Coarse partition of edges into K1 dst-buckets
    hipMemsetAsync(ghist, 0, K1 * 4, stream);
    hist_coarse<<<782, 256, 0, stream>>>(edst, ghist);
    scan_coarse<<<1, 128, 0, stream>>>(ghist, boffs, gcur);
    partition_edges<<<NCHUNK, 256, 0, stream>>>(esrc, edst, eval, gcur, recs);

    // Fused bin + segmented reduce + bias
    bucket_reduce<<<K1 * 8, 256, 0, stream>>>(Sb, recs, boffs, bias, out);
}

// Round 4
// 564.243 us; speedup vs baseline: 5.4947x; 5.4947x over previous
//
#include <hip/hip_runtime.h>

#define N_NODES 100000
#define N_EDGES 3200000
#define D 128

#define K1C    782        // coarse buckets: bucket = dst >> 7 (128 nodes each)
#define CHUNK  2048       // edges per partition block
#define NCHUNK 1563       // ceil(N_EDGES / CHUNK)

// ---------------------------------------------------------------------------
// Workspace layout (bytes). Total ~77.3 MB; round-2 proved ws >= 78,000,512.
// ---------------------------------------------------------------------------
static const size_t OFF_SB    = 0;           // S bf16: N*D*2   = 25,600,000
static const size_t OFF_REC   = 25600000;    // E int2 (coarse) = 25,600,000
static const size_t OFF_SORT2 = 51200000;    // E int2 (fine)   = 25,600,000
static const size_t OFF_OFFS  = 76800000;    // N ints          =    400,000
static const size_t OFF_GHIST = 77200000;    // K1C ints
static const size_t OFF_BOFFS = 77204096;    // K1C+1 ints
static const size_t OFF_GCUR  = 77208192;    // K1C ints

__device__ __forceinline__ unsigned short f2bf(float f) {
    unsigned u = __float_as_uint(f);
    return (unsigned short)((u + 0x7FFFu + ((u >> 16) & 1u)) >> 16);   // RNE
}

// ---------------------------------------------------------------------------
// S = X @ W, bf16 output. Lane owns features (2l, 2l+1): one packed uint per
// lane per row -> 4 B/lane gathers downstream. W staged in LDS.
// ---------------------------------------------------------------------------
__global__ __launch_bounds__(256) void gemm_xw(const float* __restrict__ X,
                                               const float* __restrict__ W,
                                               unsigned* __restrict__ Sb) {
    __shared__ float w_lds[D * D];      // 64 KB
    __shared__ float x_lds[4][D];

    for (int i = threadIdx.x; i < (D * D) / 4; i += 256)
        ((float4*)w_lds)[i] = ((const float4*)W)[i];
    __syncthreads();

    const int wave = threadIdx.x >> 6;
    const int lane = threadIdx.x & 63;

    for (int node = blockIdx.x * 4 + wave; node < N_NODES;
         node += gridDim.x * 4) {
        float2 xv = ((const float2*)(X + (size_t)node * D))[lane];
        x_lds[wave][2 * lane]     = xv.x;
        x_lds[wave][2 * lane + 1] = xv.y;

        float acc0 = 0.f, acc1 = 0.f;
#pragma unroll 8
        for (int k = 0; k < D; ++k) {
            float xk = x_lds[wave][k];                         // broadcast
            float2 w2 = ((const float2*)w_lds)[k * 64 + lane]; // conflict-free b64
            acc0 += xk * w2.x;
            acc1 += xk * w2.y;
        }
        unsigned packed = (unsigned)f2bf(acc0) | ((unsigned)f2bf(acc1) << 16);
        Sb[(size_t)node * 64 + lane] = packed;
    }
}

// ---------------------------------------------------------------------------
// Coarse histogram over K1C buckets (LDS hist, one global flush per block)
// ---------------------------------------------------------------------------
__global__ __launch_bounds__(256) void hist_coarse(const int* __restrict__ edst,
                                                   int* __restrict__ ghist) {
    __shared__ int h[K1C];
    for (int i = threadIdx.x; i < K1C; i += 256) h[i] = 0;
    __syncthreads();
    for (int e = blockIdx.x * 256 + threadIdx.x; e < N_EDGES; e += gridDim.x * 256)
        atomicAdd(&h[edst[e] >> 7], 1);
    __syncthreads();
    for (int i = threadIdx.x; i < K1C; i += 256)
        if (h[i]) atomicAdd(&ghist[i], h[i]);
}

// Exclusive scan of K1C counters -> boffs[0..K1C], gcursor = copy of boffs.
__global__ __launch_bounds__(256) void scan_coarse(const int* __restrict__ ghist,
                                                   int* __restrict__ boffs,
                                                   int* __restrict__ gcursor) {
    __shared__ int sc[256];
    const int t = threadIdx.x;
    int v[4]; int s = 0;
#pragma unroll
    for (int j = 0; j < 4; ++j) {
        int idx = t * 4 + j;
        v[j] = (idx < K1C) ? ghist[idx] : 0;
        s += v[j];
    }
    sc[t] = s;
    __syncthreads();
    for (int off = 1; off < 256; off <<= 1) {
        int u = (t >= off) ? sc[t - off] : 0;
        __syncthreads();
        sc[t] += u;
        __syncthreads();
    }
    int run = (t == 0) ? 0 : sc[t - 1];
#pragma unroll
    for (int j = 0; j < 4; ++j) {
        int idx = t * 4 + j;
        if (idx < K1C) { boffs[idx] = run; gcursor[idx] = run; }
        run += v[j];
    }
    if (t == 255) boffs[K1C] = run;   // == total = N_EDGES
}

// ---------------------------------------------------------------------------
// LDS-staged coarse partition. One block per 2048-edge chunk: bin by bucket
// in LDS, ONE returning atomic per (bucket,chunk), flush segments so each
// bucket's global stream is append-only (782 tail lines stay L2-resident ->
// writes combine to ~payload size).
// rec.x = src | (dst&127)<<17 ; rec.y = val bits.
// ---------------------------------------------------------------------------
__global__ __launch_bounds__(256) void partition_edges(
        const int* __restrict__ esrc,
        const int* __restrict__ edst,
        const float* __restrict__ eval,
        int* __restrict__ gcursor,
        int2* __restrict__ rec_out) {
    __shared__ int  hist[K1C];
    __shared__ int  lofs[K1C];
    __shared__ int  gbase[K1C];
    __shared__ int  sc[256];
    __shared__ int2 staged[CHUNK];              // 16 KB
    __shared__ unsigned short bkt[CHUNK];       // 4 KB

    const int t   = threadIdx.x;
    const int e0  = blockIdx.x * CHUNK;
    const int cnt = min(CHUNK, N_EDGES - e0);

    for (int i = t; i < K1C; i += 256) hist[i] = 0;
    __syncthreads();

    int b[8], r[8], sv[8]; float vv[8];
#pragma unroll
    for (int j = 0; j < 8; ++j) {
        int idx = t + j * 256;
        if (idx < cnt) {
            int e = e0 + idx;
            int d = edst[e];
            sv[j] = esrc[e] | ((d & 127) << 17);
            vv[j] = eval[e];
            b[j]  = d >> 7;
            r[j]  = atomicAdd(&hist[b[j]], 1);
        } else b[j] = -1;
    }
    __syncthreads();

    // exclusive scan of hist -> lofs; reserve global space per bucket
    int hv[4]; int hs = 0;
#pragma unroll
    for (int j = 0; j < 4; ++j) {
        int idx = t * 4 + j;
        hv[j] = (idx < K1C) ? hist[idx] : 0;
        hs += hv[j];
    }
    sc[t] = hs;
    __syncthreads();
    for (int off = 1; off < 256; off <<= 1) {
        int u = (t >= off) ? sc[t - off] : 0;
        __syncthreads();
        sc[t] += u;
        __syncthreads();
    }
    int run = (t == 0) ? 0 : sc[t - 1];
#pragma unroll
    for (int j = 0; j < 4; ++j) {
        int idx = t * 4 + j;
        if (idx < K1C) {
            lofs[idx]  = run;
            gbase[idx] = hv[j] ? atomicAdd(&gcursor[idx], hv[j]) : 0;
        }
        run += hv[j];
    }
    __syncthreads();

#pragma unroll
    for (int j = 0; j < 8; ++j) {
        if (b[j] >= 0) {
            int pos = lofs[b[j]] + r[j];
            staged[pos] = make_int2(sv[j], __float_as_int(vv[j]));
            bkt[pos] = (unsigned short)b[j];
        }
    }
    __syncthreads();

    for (int i = t; i < cnt; i += 256) {
        int bb = bkt[i];
        rec_out[gbase[bb] + (i - lofs[bb])] = staged[i];
    }
}

// ---------------------------------------------------------------------------
// Fine sort within each coarse bucket (one block per bucket). The scatter
// window is ~32 KB -> fully L2-resident -> full-line evictions. Also emits
// per-node segment offsets for the reducer.
// ---------------------------------------------------------------------------
__global__ __launch_bounds__(256) void fine_sort(
        const int2* __restrict__ rec,
        const int* __restrict__ boffs,
        int* __restrict__ offs,
        int2* __restrict__ sorted2) {
    __shared__ int h[128];
    __shared__ int cur[128];
    __shared__ int sc[256];

    const int c   = blockIdx.x;
    const int t   = threadIdx.x;
    const int beg = boffs[c];
    const int end = boffs[c + 1];

    if (t < 128) h[t] = 0;
    __syncthreads();

    for (int i = beg + t; i < end; i += 256)
        atomicAdd(&h[(rec[i].x >> 17) & 127], 1);
    __syncthreads();

    sc[t] = (t < 128) ? h[t] : 0;
    __syncthreads();
    for (int off = 1; off < 128; off <<= 1) {
        int u = (t >= off) ? sc[t - off] : 0;
        __syncthreads();
        sc[t] += u;
        __syncthreads();
    }
    if (t < 128) {
        int excl = (t == 0) ? 0 : sc[t - 1];
        int node = c * 128 + t;
        if (node < N_NODES) offs[node] = beg + excl;
        cur[t] = beg + excl;
    }
    __syncthreads();

    for (int i = beg + t; i < end; i += 256) {
        int2 q = rec[i];
        int dl = (q.x >> 17) & 127;
        int p = atomicAdd(&cur[dl], 1);
        sorted2[p] = make_int2(q.x & 0x1FFFF, q.y);
    }
}

// ---------------------------------------------------------------------------
// One wave per dst node: coalesced 64-wide record load, shfl broadcast,
// coalesced 4 B/lane bf16 gathers (2-way ILP), register acc, biased store.
// ---------------------------------------------------------------------------
__global__ __launch_bounds__(256) void reduce_segments(
        const unsigned short* __restrict__ Sb,
        const int2* __restrict__ sorted,
        const int* __restrict__ offs,
        const float* __restrict__ bias,
        float* __restrict__ out) {
    const int lane = threadIdx.x & 63;
    const int node = (blockIdx.x * 256 + threadIdx.x) >> 6;
    if (node >= N_NODES) return;

    const int beg = offs[node];
    const int end = (node == N_NODES - 1) ? N_EDGES : offs[node + 1];

    float acc0x = 0.f, acc0y = 0.f, acc1x = 0.f, acc1y = 0.f;

    for (int base = beg; base < end; base += 64) {
        const int m = min(64, end - base);
        int2 rec = make_int2(0, 0);
        if (base + lane < end) rec = sorted[base + lane];

        int j = 0;
        for (; j + 1 < m; j += 2) {
            int   s0 = __shfl(rec.x, j);
            float v0 = __int_as_float(__shfl(rec.y, j));
            int   s1 = __shfl(rec.x, j + 1);
            float v1 = __int_as_float(__shfl(rec.y, j + 1));
            unsigned p0 = *(const unsigned*)(Sb + ((size_t)s0 << 7) + 2 * lane);
            unsigned p1 = *(const unsigned*)(Sb + ((size_t)s1 << 7) + 2 * lane);
            acc0x += v0 * __uint_as_float(p0 << 16);
            acc0y += v0 * __uint_as_float(p0 & 0xFFFF0000u);
            acc1x += v1 * __uint_as_float(p1 << 16);
            acc1y += v1 * __uint_as_float(p1 & 0xFFFF0000u);
        }
        if (j < m) {
            int   s0 = __shfl(rec.x, j);
            float v0 = __int_as_float(__shfl(rec.y, j));
            unsigned p0 = *(const unsigned*)(Sb + ((size_t)s0 << 7) + 2 * lane);
            acc0x += v0 * __uint_as_float(p0 << 16);
            acc0y += v0 * __uint_as_float(p0 & 0xFFFF0000u);
        }
    }

    float2 b2 = ((const float2*)bias)[lane];
    float2 r2 = make_float2(acc0x + acc1x + b2.x, acc0y + acc1y + b2.y);
    ((float2*)(out + (size_t)node * D))[lane] = r2;
}

extern "C" void kernel_launch(void* const* d_in, const int* in_sizes, int n_in,
                              void* d_out, int out_size, void* d_ws, size_t ws_size,
                              hipStream_t stream) {
    const float* X    = (const float*)d_in[0];
    const int*   esrc = (const int*)  d_in[1];
    const int*   edst = (const int*)  d_in[2];
    const float* eval = (const float*)d_in[3];
    const float* W    = (const float*)d_in[4];
    const float* bias = (const float*)d_in[5];
    float* out = (float*)d_out;

    char* ws = (char*)d_ws;
    unsigned*       SbW   = (unsigned*)      (ws + OFF_SB);
    unsigned short* Sb    = (unsigned short*)(ws + OFF_SB);
    int2*           recs  = (int2*)          (ws + OFF_REC);
    int2*           srt2  = (int2*)          (ws + OFF_SORT2);
    int*            offs  = (int*)           (ws + OFF_OFFS);
    int*            ghist = (int*)           (ws + OFF_GHIST);
    int*            boffs = (int*)           (ws + OFF_BOFFS);
    int*            gcur  = (int*)           (ws + OFF_GCUR);

    // S = X @ W (bf16)
    gemm_xw<<<2048, 256, 0, stream>>>(X, W, SbW);

    // Two-level counting sort of edges by dst (all scatters L2-resident)
    hipMemsetAsync(ghist, 0, K1C * 4, stream);
    hist_coarse<<<782, 256, 0, stream>>>(edst, ghist);
    scan_coarse<<<1, 256, 0, stream>>>(ghist, boffs, gcur);
    partition_edges<<<NCHUNK, 256, 0, stream>>>(esrc, edst, eval, gcur, recs);
    fine_sort<<<K1C, 256, 0, stream>>>(recs, boffs, offs, srt2);

    // Segmented reduce: out[n] = bias + sum val * S[src]
    reduce_segments<<<(N_NODES + 3) / 4, 256, 0, stream>>>(
        Sb, srt2, offs, bias, out);
}